// Round 1
// 110.569 us; speedup vs baseline: 1.0064x; 1.0064x over previous
//
#include <hip/hip_runtime.h>
#include <math.h>

#define BB 16
#define AA 262144
#define GG 128
#define TPB 256
#define NBLK (AA / TPB)   // 1024 blocks, 1 anchor per thread

// ws layout (floats):
//   [0 .. BB*NBLK)           per-image per-block l1 sums
//   [BB*NBLK .. 2*BB*NBLK)   per-image per-block fg counts

__global__ __launch_bounds__(TPB, 3) void loss_main_kernel(
    const float4* __restrict__ reg,    // [B*A]
    const float4* __restrict__ anc,    // [A]
    const float4* __restrict__ gt,     // [B*G]
    const int*   __restrict__ mi,      // [B*A]
    float* __restrict__ ws_sum,        // [BB*NBLK]
    float* __restrict__ ws_cnt)        // [BB*NBLK]
{
    __shared__ float4 gts[BB * GG];    // 32 KB: (cx, cy, log w, log h)
    __shared__ float  S[BB][TPB];      // 16 KB: transposed per-thread l1 values
    __shared__ float  redC[BB * 4];

    const int t  = threadIdx.x;
    const int bx = blockIdx.x;
    const int a  = bx * TPB + t;

    // ---- issue ALL global loads up front (max MLP) ----
    // gt staging loads first (they gate the barrier)
    float4 gload[(BB * GG) / TPB];
#pragma unroll
    for (int i = 0; i < (BB * GG) / TPB; ++i)
        gload[i] = gt[i * TPB + t];

    // matched indices: 16 scalar loads
    int mjv[BB];
#pragma unroll
    for (int b = 0; b < BB; ++b) mjv[b] = mi[b * AA + a];

    // regression rows: 16 float4 loads
    float4 r[BB];
#pragma unroll
    for (int b = 0; b < BB; ++b) r[b] = reg[b * AA + a];

    const float4 an = anc[a];

    // ---- stage gt boxes pre-transformed (waits only on gload) ----
#pragma unroll
    for (int i = 0; i < (BB * GG) / TPB; ++i) {
        const float4 g = gload[i];
        const float w = g.z - g.x;
        const float h = g.w - g.y;
        gts[i * TPB + t] = make_float4(g.x + 0.5f * w, g.y + 0.5f * h,
                                       __logf(w), __logf(h));
    }

    // per-anchor invariants
    const float ex_w  = an.z - an.x;
    const float ex_h  = an.w - an.y;
    const float ex_cx = an.x + 0.5f * ex_w;
    const float ex_cy = an.y + 0.5f * ex_h;
    const float inv_w = 1.0f / ex_w;
    const float inv_h = 1.0f / ex_h;
    const float lw    = __logf(ex_w);
    const float lh    = __logf(ex_h);

    __syncthreads();   // gts ready

    const int wv   = t >> 6;
    const int lane = t & 63;

    // ---- main loop: 1 conflict-free ds_write per image (no shuffle trees) ----
#pragma unroll
    for (int b = 0; b < BB; ++b) {
        const int mj = mjv[b];
        const float4 g = gts[b * GG + (mj < 0 ? 0 : mj)];

        const float dx = (g.x - ex_cx) * inv_w;
        const float dy = (g.y - ex_cy) * inv_h;
        const float dw = g.z - lw;
        const float dh = g.w - lh;

        const float l1 = fabsf(r[b].x - dx) + fabsf(r[b].y - dy) +
                         fabsf(r[b].z - dw) + fabsf(r[b].w - dh);

        S[b][t] = (mj >= 0) ? l1 : 0.0f;   // addr = b*256+t: lanes consecutive -> conflict-free

        const unsigned long long bal = __ballot(mj >= 0);
        if (lane == 0) redC[b * 4 + wv] = (float)__popcll(bal);
    }
    __syncthreads();

    // ---- cooperative block reduction (once per block) ----
    // thread t: image b = t>>4, chunk c = t&15 sums 16 strided values,
    // then a 4-step shuffle folds the 16 chunk-partials (contiguous lanes).
    {
        const int b = t >> 4;
        const int c = t & 15;
        float p = 0.0f;
#pragma unroll
        for (int j = 0; j < 16; ++j) p += S[b][c + 16 * j];
#pragma unroll
        for (int o = 8; o > 0; o >>= 1) p += __shfl_down(p, o);
        if (c == 0) {
            ws_sum[b * NBLK + bx] = p;
            ws_cnt[b * NBLK + bx] = redC[b * 4] + redC[b * 4 + 1] +
                                    redC[b * 4 + 2] + redC[b * 4 + 3];
        }
    }
}

// single block: each wave reduces 4 images, thread 0 combines
__global__ __launch_bounds__(TPB) void reduce_final_kernel(
    const float* __restrict__ ws_sum,
    const float* __restrict__ ws_cnt,
    float* __restrict__ out)
{
    __shared__ float per_img[BB];
    const int t    = threadIdx.x;
    const int wv   = t >> 6;
    const int lane = t & 63;

#pragma unroll
    for (int k = 0; k < 4; ++k) {
        const int b = wv * 4 + k;
        float s = 0.0f, c = 0.0f;
#pragma unroll
        for (int i = 0; i < NBLK / 64; ++i) {
            s += ws_sum[b * NBLK + i * 64 + lane];
            c += ws_cnt[b * NBLK + i * 64 + lane];
        }
#pragma unroll
        for (int o = 32; o > 0; o >>= 1) {
            s += __shfl_down(s, o);
            c += __shfl_down(c, o);
        }
        if (lane == 0) per_img[b] = s / fmaxf(1.0f, c);
    }
    __syncthreads();

    if (t == 0) {
        float acc = 0.0f;
#pragma unroll
        for (int b = 0; b < BB; ++b) acc += per_img[b];
        out[0] = acc / (float)BB;
    }
}

extern "C" void kernel_launch(void* const* d_in, const int* in_sizes, int n_in,
                              void* d_out, int out_size, void* d_ws, size_t ws_size,
                              hipStream_t stream) {
    const float4* reg = (const float4*)d_in[0];   // bbox_regression [B,A,4]
    const float4* anc = (const float4*)d_in[1];   // anchors [A,4]
    const float4* gt  = (const float4*)d_in[2];   // gt_boxes [B,G,4]
    const int*    mi  = (const int*)d_in[3];      // matched_idxs [B,A]

    float* ws_sum = (float*)d_ws;
    float* ws_cnt = ws_sum + BB * NBLK;

    loss_main_kernel<<<NBLK, TPB, 0, stream>>>(reg, anc, gt, mi, ws_sum, ws_cnt);
    reduce_final_kernel<<<1, TPB, 0, stream>>>(ws_sum, ws_cnt, (float*)d_out);
}